// Round 9
// baseline (2564.037 us; speedup 1.0000x reference)
//
#include <hip/hip_runtime.h>
#include <cstdint>
#include <cstddef>

#define NTOK 8192
#define NE 512
#define EDIM 256
#define NEXPALL 11
#define NITER 100

static __device__ __forceinline__ double wredsum(double x) {
  for (int o = 32; o > 0; o >>= 1) x += __shfl_down(x, o, 64);
  return x;
}

static constexpr double S32 = 2.3283064365386963e-10; // 2^-32
static constexpr double Q32 = 4294967296.0;           // 2^32

// ---------------- init ----------------
__global__ void k_init(unsigned* colmin, double* r0, double* uprev,
                       unsigned* dmaxA, unsigned* dminA, int* conv_iter, double* sums) {
  int i = blockIdx.x * 256 + threadIdx.x;
  if (i < NEXPALL * NTOK) colmin[i] = 0x7F800000u; // +inf f32
  if (i < NEXPALL * NE) { r0[i] = 0.0; uprev[i] = 0.0; }
  if (i < NEXPALL) { dmaxA[i] = 0u; dminA[i] = 0x7F800000u; conv_iter[i] = 1 << 30; }
  if (i < 2) sums[i] = 0.0;
}

// ---------------- numpy-pairwise sum of squares (f32, bit-exact tree) ----------------
__global__ __launch_bounds__(256) void k_npsq(const float* __restrict__ p, float* __restrict__ o, int rows) {
  int r = blockIdx.x * 16 + (threadIdx.x >> 4);
  int l = threadIdx.x & 15;
  if (r >= rows) return;
  const float* a = p + (size_t)r * EDIM;
  int leaf = l >> 3;
  int j = l & 7;
  const float* base = a + leaf * 128 + j;
  float acc = __fmul_rn(base[0], base[0]);
#pragma unroll
  for (int i = 8; i < 128; i += 8) {
    float v = base[i];
    acc = __fadd_rn(acc, __fmul_rn(v, v));
  }
  acc = __fadd_rn(acc, __shfl_xor(acc, 1, 64));
  acc = __fadd_rn(acc, __shfl_xor(acc, 2, 64));
  acc = __fadd_rn(acc, __shfl_xor(acc, 4, 64));
  float other = __shfl_xor(acc, 8, 64);
  float tot = (leaf == 0) ? __fadd_rn(acc, other) : __fadd_rn(other, acc);
  if (l == 0) o[r] = tot;
}

// ---------------- K1: f32 GEMM, 128x128 tile, 8x8 reg tile, DOUBLE-BUFFERED LDS ------
// One barrier per k-tile (vs 2): prefetch t+1 -> regs before compute (loads hide
// under the fma phase), write regs -> alternate buffer after compute, single
// __syncthreads. Per-output fmaf chain unchanged -> bit-identical d.
// (256,2) measured-good (VGPR 116, no spill); (256,4) spilled (round-4 lesson).
__global__ __launch_bounds__(256, 2) void k_gemm_d(const float* __restrict__ x, const float* __restrict__ emb,
                                                   const float* __restrict__ sx, const float* __restrict__ sw,
                                                   float* __restrict__ bigF,
                                                   unsigned* __restrict__ colminA,
                                                   unsigned* __restrict__ dmaxA,
                                                   unsigned* __restrict__ dminA) {
  int bx = blockIdx.x, by = blockIdx.y, e = blockIdx.z;
  int tid = threadIdx.x;
  int tx = tid & 15, ty = tid >> 4;
  int b0 = bx * 128, k0 = by * 128;

  __shared__ float xs[2][16][128]; // [buf][k][token]
  __shared__ float es[2][16][128]; // [buf][k][code]
  __shared__ float sxs[128];
  __shared__ float sws[128];
  __shared__ unsigned colm[128];
  __shared__ float wrx[4], wrn[4];

  if (tid < 128) { sxs[tid] = sx[b0 + tid]; colm[tid] = 0x7F800000u; }
  else { sws[tid - 128] = sw[e * NE + k0 + tid - 128]; }

  int lr = tid & 127;  // token / code row for staging
  int lh = tid >> 7;   // k sub-offset 0 or 8
  const float* xrow = x + (size_t)(b0 + lr) * EDIM + lh * 8;
  const float* wrow = emb + ((size_t)e * NE + k0 + lr) * EDIM + lh * 8;

  float4 xa = *(const float4*)(xrow + 0);
  float4 xb = *(const float4*)(xrow + 4);
  float4 wa = *(const float4*)(wrow + 0);
  float4 wb = *(const float4*)(wrow + 4);

  // stage tile 0 into buf 0
  xs[0][lh * 8 + 0][lr] = xa.x; xs[0][lh * 8 + 1][lr] = xa.y;
  xs[0][lh * 8 + 2][lr] = xa.z; xs[0][lh * 8 + 3][lr] = xa.w;
  xs[0][lh * 8 + 4][lr] = xb.x; xs[0][lh * 8 + 5][lr] = xb.y;
  xs[0][lh * 8 + 6][lr] = xb.z; xs[0][lh * 8 + 7][lr] = xb.w;
  es[0][lh * 8 + 0][lr] = wa.x; es[0][lh * 8 + 1][lr] = wa.y;
  es[0][lh * 8 + 2][lr] = wa.z; es[0][lh * 8 + 3][lr] = wa.w;
  es[0][lh * 8 + 4][lr] = wb.x; es[0][lh * 8 + 5][lr] = wb.y;
  es[0][lh * 8 + 6][lr] = wb.z; es[0][lh * 8 + 7][lr] = wb.w;
  __syncthreads();

  float acc[8][8] = {};

  for (int it = 0; it < 16; ++it) {
    int cur = it & 1;
    if (it < 15) { // prefetch next tile; latency hides under compute below
      int kc = (it + 1) * 16;
      xa = *(const float4*)(xrow + kc);
      xb = *(const float4*)(xrow + kc + 4);
      wa = *(const float4*)(wrow + kc);
      wb = *(const float4*)(wrow + kc + 4);
    }
    float (*xsb)[128] = xs[cur];
    float (*esb)[128] = es[cur];
#pragma unroll
    for (int kk = 0; kk < 16; ++kk) {
      float4 xv0 = *(const float4*)&xsb[kk][tx * 4];
      float4 xv1 = *(const float4*)&xsb[kk][64 + tx * 4];
      float4 wv0 = *(const float4*)&esb[kk][ty * 4];
      float4 wv1 = *(const float4*)&esb[kk][64 + ty * 4];
      float xr[8] = {xv0.x, xv0.y, xv0.z, xv0.w, xv1.x, xv1.y, xv1.z, xv1.w};
      float wr[8] = {wv0.x, wv0.y, wv0.z, wv0.w, wv1.x, wv1.y, wv1.z, wv1.w};
#pragma unroll
      for (int i = 0; i < 8; ++i)
#pragma unroll
        for (int j = 0; j < 8; ++j)
          acc[i][j] = fmaf(xr[i], wr[j], acc[i][j]);
    }
    if (it < 15) { // stage next tile into alternate buffer; ONE barrier per tile
      int nb = cur ^ 1;
      xs[nb][lh * 8 + 0][lr] = xa.x; xs[nb][lh * 8 + 1][lr] = xa.y;
      xs[nb][lh * 8 + 2][lr] = xa.z; xs[nb][lh * 8 + 3][lr] = xa.w;
      xs[nb][lh * 8 + 4][lr] = xb.x; xs[nb][lh * 8 + 5][lr] = xb.y;
      xs[nb][lh * 8 + 6][lr] = xb.z; xs[nb][lh * 8 + 7][lr] = xb.w;
      es[nb][lh * 8 + 0][lr] = wa.x; es[nb][lh * 8 + 1][lr] = wa.y;
      es[nb][lh * 8 + 2][lr] = wa.z; es[nb][lh * 8 + 3][lr] = wa.w;
      es[nb][lh * 8 + 4][lr] = wb.x; es[nb][lh * 8 + 5][lr] = wb.y;
      es[nb][lh * 8 + 6][lr] = wb.z; es[nb][lh * 8 + 7][lr] = wb.w;
      __syncthreads();
    }
  }

  // epilogue: d = sx + sw - 2*acc (in place), stats, transposed store
  float dmx = -3.0e38f, dmn = 3.0e38f;
#pragma unroll
  for (int i = 0; i < 8; ++i) {
    int tokL = (i >> 2) * 64 + tx * 4 + (i & 3);
    float sxv = sxs[tokL];
    float cmin = 3.0e38f;
#pragma unroll
    for (int j = 0; j < 8; ++j) {
      int codeL = (j >> 2) * 64 + ty * 4 + (j & 3);
      float m2 = __fmul_rn(2.0f, acc[i][j]);
      float dv = __fsub_rn(__fadd_rn(sxv, sws[codeL]), m2);
      acc[i][j] = dv;
      dmx = fmaxf(dmx, dv); dmn = fminf(dmn, dv);
      cmin = fminf(cmin, dv);
    }
    atomicMin(&colm[tokL], __float_as_uint(cmin)); // d > 0 -> uint order == float order
  }
  for (int o = 32; o > 0; o >>= 1) {
    dmx = fmaxf(dmx, __shfl_down(dmx, o, 64));
    dmn = fminf(dmn, __shfl_down(dmn, o, 64));
  }
  int wvi = tid >> 6, ln = tid & 63;
  if (ln == 0) { wrx[wvi] = dmx; wrn[wvi] = dmn; }
  __syncthreads();
  if (tid == 0) {
    float m1 = fmaxf(fmaxf(wrx[0], wrx[1]), fmaxf(wrx[2], wrx[3]));
    float m2 = fminf(fminf(wrn[0], wrn[1]), fminf(wrn[2], wrn[3]));
    atomicMax(dmaxA + e, __float_as_uint(m1));
    atomicMin(dminA + e, __float_as_uint(m2));
  }
  if (tid < 128) atomicMin(colminA + (size_t)e * NTOK + b0 + tid, colm[tid]);
#pragma unroll
  for (int j2 = 0; j2 < 2; ++j2)
#pragma unroll
    for (int cc = 0; cc < 4; ++cc) {
      int code = j2 * 64 + ty * 4 + cc;
      int cj = j2 * 4 + cc;
      float* ob = bigF + ((size_t)e * NE + k0 + code) * NTOK + b0;
      float4 lo = make_float4(acc[0][cj], acc[1][cj], acc[2][cj], acc[3][cj]);
      float4 hi = make_float4(acc[4][cj], acc[5][cj], acc[6][cj], acc[7][cj]);
      *(float4*)(ob + tx * 4) = lo;
      *(float4*)(ob + 64 + tx * 4) = hi;
    }
}

// ---------------- K2: per-token colmax logit + v0 ----------------
__global__ __launch_bounds__(256) void k_prep(const unsigned* __restrict__ colminA,
                                              const unsigned* __restrict__ dmaxA,
                                              const unsigned* __restrict__ dminA,
                                              double* __restrict__ cml, double* __restrict__ v) {
  int e = blockIdx.y;
  int b = blockIdx.x * 256 + threadIdx.x;
  float mx = __uint_as_float(dmaxA[e]);
  float mn = __uint_as_float(dminA[e]);
  float mid = __fmul_rn(__fadd_rn(mx, mn), 0.5f);
  float amp = __fadd_rn(__fsub_rn(mx, mid), 1e-5f);
  float cminf = __uint_as_float(colminA[(size_t)e * NTOK + b]);
  float dn = __fdiv_rn(__fsub_rn(cminf, mid), amp);
  double l = (-(double)dn) / 0.01;
  cml[(size_t)e * NTOK + b] = l;
  v[(size_t)e * NTOK + b] = exp(l);
}

// ---------------- K3: build B (u32 fixed point of 1-B, in place) + r0 ----------------
__global__ __launch_bounds__(256) void k_build(float* __restrict__ bigF,
                                               const unsigned* __restrict__ dmaxA,
                                               const unsigned* __restrict__ dminA,
                                               const double* __restrict__ cml, const double* __restrict__ v0,
                                               double* __restrict__ r0) {
  int bx = blockIdx.x, k = blockIdx.y, e = blockIdx.z;
  int tid = threadIdx.x;
  float mx = __uint_as_float(dmaxA[e]);
  float mn = __uint_as_float(dminA[e]);
  float mid = __fmul_rn(__fadd_rn(mx, mn), 0.5f);
  float amp = __fadd_rn(__fsub_rn(mx, mid), 1e-5f);
  size_t rb = ((size_t)e * NE + k) * NTOK;
  int cb = bx * 2048 + tid * 8;
  float4 fa = *(const float4*)(bigF + rb + cb);
  float4 fb = *(const float4*)(bigF + rb + cb + 4);
  float din[8] = {fa.x, fa.y, fa.z, fa.w, fb.x, fb.y, fb.z, fb.w};
  unsigned qo[8];
  double racc = 0.0;
#pragma unroll
  for (int j = 0; j < 8; ++j) {
    int b = cb + j;
    float dn = __fdiv_rn(__fsub_rn(din[j], mid), amp);
    double l = (-(double)dn) / 0.01;
    double t = l - cml[(size_t)e * NTOK + b]; // <= 0, == 0 at per-token max logit
    double Bv = exp(t);
    double qd = (1.0 - Bv) * Q32;
    qd = fmin(fmax(qd, 0.0), 4294967295.0);
    unsigned q = (unsigned)llrint(qd);
    qo[j] = q;
    double Bq = fma(-(double)q, S32, 1.0);
    racc = fma(Bq, v0[(size_t)e * NTOK + b], racc);
  }
  uint4 oa = make_uint4(qo[0], qo[1], qo[2], qo[3]);
  uint4 ob2 = make_uint4(qo[4], qo[5], qo[6], qo[7]);
  *(uint4*)((unsigned*)bigF + rb + cb) = oa;
  *(uint4*)((unsigned*)bigF + rb + cb + 4) = ob2;
  racc = wredsum(racc);
  __shared__ double pr[4];
  int wv = tid >> 6, ln = tid & 63;
  if (ln == 0) pr[wv] = racc;
  __syncthreads();
  if (tid == 0) atomicAdd(&r0[e * NE + k], (pr[0] + pr[1]) + (pr[2] + pr[3]));
}

// ---------------- K4a: col sums -> v (uint4: 4 cols/thread, 8 k-slices) --------------
__global__ __launch_bounds__(256) void k_colsum(const unsigned* __restrict__ bigU,
                                                const double* __restrict__ rsrc,
                                                double* __restrict__ vout,
                                                double* __restrict__ uprev,
                                                int* __restrict__ conv_iter, int t) {
  int e = blockIdx.y, sub = blockIdx.x, tid = threadIdx.x;
  if (t > ((volatile int*)conv_iter)[e]) return;
  __shared__ double us[NE];
  __shared__ double part[8][128];
  __shared__ int okf;
  if (tid == 0) okf = 1;
  int k2 = tid * 2;
  double u0 = 1.0 / (512.0 * rsrc[e * NE + k2]);
  double u1 = 1.0 / (512.0 * rsrc[e * NE + k2 + 1]);
  us[k2] = u0; us[k2 + 1] = u1;
  __syncthreads();
  if (sub == 0) {
    double p0 = uprev[e * NE + k2], p1 = uprev[e * NE + k2 + 1];
    bool ok = (fabs(u0 - p0) <= 1e-13 * fabs(u0)) && (fabs(u1 - p1) <= 1e-13 * fabs(u1));
    if (!ok) okf = 0;
    uprev[e * NE + k2] = u0; uprev[e * NE + k2 + 1] = u1;
  }
  __syncthreads();
  if (sub == 0 && tid == 0 && okf) atomicMin(conv_iter + e, t);

  int cq = tid & 31;  // col-quad within stripe
  int ks = tid >> 5;  // k-slice
  int colb = sub * 128 + cq * 4;
  const unsigned* cp = bigU + (size_t)e * NE * NTOK + (size_t)(ks * 64) * NTOK + colb;
  double c0 = 0, c1 = 0, c2 = 0, c3 = 0;
#pragma unroll 4
  for (int kk = 0; kk < 64; ++kk) {
    uint4 q = *(const uint4*)(cp + (size_t)kk * NTOK);
    double uk = us[ks * 64 + kk];
    c0 = fma(uk, fma(-(double)q.x, S32, 1.0), c0);
    c1 = fma(uk, fma(-(double)q.y, S32, 1.0), c1);
    c2 = fma(uk, fma(-(double)q.z, S32, 1.0), c2);
    c3 = fma(uk, fma(-(double)q.w, S32, 1.0), c3);
  }
  part[ks][cq * 4 + 0] = c0;
  part[ks][cq * 4 + 1] = c1;
  part[ks][cq * 4 + 2] = c2;
  part[ks][cq * 4 + 3] = c3;
  __syncthreads();
  if (tid < 128) {
    double s = ((part[0][tid] + part[1][tid]) + (part[2][tid] + part[3][tid]))
             + ((part[4][tid] + part[5][tid]) + (part[6][tid] + part[7][tid]));
    vout[(size_t)e * NTOK + sub * 128 + tid] = 1.0 / (8192.0 * s);
  }
}

// ---------------- K4b: row sums -> racc (plain stores; block owns its k's) ----------
__global__ __launch_bounds__(256) void k_rowsum(const unsigned* __restrict__ bigU,
                                                const double* __restrict__ v,
                                                double* __restrict__ racc,
                                                const int* __restrict__ conv_iter, int t) {
  int e = blockIdx.y, sub = blockIdx.x, tid = threadIdx.x;
  if (t > ((volatile int*)conv_iter)[e]) return;
  size_t ebase = (size_t)e * NE * NTOK;
  const double* vb = v + (size_t)e * NTOK;
  double p[8] = {0, 0, 0, 0, 0, 0, 0, 0};
  for (int i = 0; i < 8; ++i) {
    int c = i * 1024 + tid * 4;
    double2 va = *(const double2*)(vb + c);
    double2 vc = *(const double2*)(vb + c + 2);
#pragma unroll
    for (int kk = 0; kk < 8; ++kk) {
      const unsigned* rp = bigU + ebase + (size_t)(sub * 8 + kk) * NTOK + c;
      uint4 q = *(const uint4*)rp;
      p[kk] = fma(va.x, fma(-(double)q.x, S32, 1.0), p[kk]);
      p[kk] = fma(va.y, fma(-(double)q.y, S32, 1.0), p[kk]);
      p[kk] = fma(vc.x, fma(-(double)q.z, S32, 1.0), p[kk]);
      p[kk] = fma(vc.y, fma(-(double)q.w, S32, 1.0), p[kk]);
    }
  }
  __shared__ double pr[8][4];
  int wv = tid >> 6, ln = tid & 63;
#pragma unroll
  for (int kk = 0; kk < 8; ++kk) {
    double s = wredsum(p[kk]);
    if (ln == 0) pr[kk][wv] = s;
  }
  __syncthreads();
  if (tid < 8)
    racc[e * NE + sub * 8 + tid] = (pr[tid][0] + pr[tid][1]) + (pr[tid][2] + pr[tid][3]);
}

// ---------------- K5: final argmax per token (u from racc; v cancels) ----------------
__global__ __launch_bounds__(256) void k_final(const unsigned* __restrict__ bigU,
                                               const double* __restrict__ racc,
                                               int* __restrict__ idxs) {
  int e = blockIdx.y, sub = blockIdx.x, tid = threadIdx.x;
  __shared__ double us[NE];
  __shared__ double bv[256];
  __shared__ int bix[256];
  int k2 = tid * 2;
  us[k2] = 1.0 / (512.0 * racc[e * NE + k2]);
  us[k2 + 1] = 1.0 / (512.0 * racc[e * NE + k2 + 1]);
  __syncthreads();
  int lcol = tid & 127, half = tid >> 7;
  int col = sub * 128 + lcol;
  const unsigned* cp = bigU + (size_t)e * NE * NTOK + col;
  double best = -1.0;
  int bi = 0;
  int kh = half * 256;
#pragma unroll 4
  for (int k = kh; k < kh + 256; ++k) {
    double s = us[k] * fma(-(double)cp[(size_t)k * NTOK], S32, 1.0);
    if (s > best) { best = s; bi = k; }
  }
  bv[tid] = best; bix[tid] = bi;
  __syncthreads();
  if (tid < 128) {
    // half-0 ks are all smaller; strict > keeps first-max semantics
    int r = (bv[tid + 128] > bv[tid]) ? bix[tid + 128] : bix[tid];
    idxs[(size_t)e * NTOK + col] = r;
  }
}

// ---------------- K6: mixture, out0, mse partial, index output ----------------
__global__ __launch_bounds__(256) void k_mix(const float* __restrict__ x, const float* __restrict__ gate,
                                             const float* __restrict__ emb, const int* __restrict__ idxs,
                                             float* __restrict__ xq, float* __restrict__ out0,
                                             float* __restrict__ outIdx, double* __restrict__ mse_sum) {
  int tid = threadIdx.x;
  int sub = tid >> 5, lane = tid & 31;
  int tok = blockIdx.x * 8 + sub;
  float acc[8] = {0, 0, 0, 0, 0, 0, 0, 0};
#pragma unroll
  for (int ee = 0; ee < 10; ++ee) {
    int id = idxs[(size_t)ee * NTOK + tok];
    float g = gate[tok * 10 + ee];
    const float* er = emb + ((size_t)ee * NE + id) * EDIM + lane;
#pragma unroll
    for (int dd = 0; dd < 8; ++dd) acc[dd] = fmaf(g, er[32 * dd], acc[dd]);
  }
  int id10 = idxs[(size_t)10 * NTOK + tok];
  const float* es = emb + ((size_t)10 * NE + id10) * EDIM + lane;
  double ms = 0.0;
#pragma unroll
  for (int dd = 0; dd < 8; ++dd) {
    int d = lane + 32 * dd;
    float q = 0.95f * acc[dd] + 0.05f * es[32 * dd];
    float xv = x[(size_t)tok * EDIM + d];
    float df = q - xv;
    out0[(size_t)tok * EDIM + d] = xv + df;
    xq[(size_t)tok * EDIM + d] = q;
    ms += (double)df * (double)df;
  }
  ms = wredsum(ms);
  __shared__ double pr[4];
  int wv = tid >> 6, ln = tid & 63;
  if (ln == 0) pr[wv] = ms;
  __syncthreads();
  if (tid == 0) atomicAdd(mse_sum, (pr[0] + pr[1]) + (pr[2] + pr[3]));
  if (lane == 0) {
    const float* gr = gate + tok * 10;
    float bg = gr[0];
    int be = 0;
#pragma unroll
    for (int ee = 1; ee < 10; ++ee) { float g = gr[ee]; if (g > bg) { bg = g; be = ee; } }
    outIdx[tok] = (float)idxs[(size_t)be * NTOK + tok];
  }
}

// ---------------- K7: sim = x_q @ emb0^T, same dbuf 128x128 / 8x8 structure ----------
__global__ __launch_bounds__(256, 2) void k_simgemm(const float* __restrict__ xq, const float* __restrict__ emb,
                                                    float* __restrict__ sim) {
  int bx = blockIdx.x, by = blockIdx.y, tid = threadIdx.x;
  int tx = tid & 15, ty = tid >> 4;
  int b0 = bx * 128, j0 = by * 128;
  __shared__ float xs[2][16][128]; // [buf][k][token]
  __shared__ float es[2][16][128]; // [buf][k][code]
  int lr = tid & 127;
  int lh = tid >> 7;
  const float* xrow = xq + (size_t)(b0 + lr) * EDIM + lh * 8;
  const float* erow = emb + (size_t)(j0 + lr) * EDIM + lh * 8; // expert 0
  float4 xa = *(const float4*)(xrow + 0);
  float4 xb = *(const float4*)(xrow + 4);
  float4 wa = *(const float4*)(erow + 0);
  float4 wb = *(const float4*)(erow + 4);
  xs[0][lh * 8 + 0][lr] = xa.x; xs[0][lh * 8 + 1][lr] = xa.y;
  xs[0][lh * 8 + 2][lr] = xa.z; xs[0][lh * 8 + 3][lr] = xa.w;
  xs[0][lh * 8 + 4][lr] = xb.x; xs[0][lh * 8 + 5][lr] = xb.y;
  xs[0][lh * 8 + 6][lr] = xb.z; xs[0][lh * 8 + 7][lr] = xb.w;
  es[0][lh * 8 + 0][lr] = wa.x; es[0][lh * 8 + 1][lr] = wa.y;
  es[0][lh * 8 + 2][lr] = wa.z; es[0][lh * 8 + 3][lr] = wa.w;
  es[0][lh * 8 + 4][lr] = wb.x; es[0][lh * 8 + 5][lr] = wb.y;
  es[0][lh * 8 + 6][lr] = wb.z; es[0][lh * 8 + 7][lr] = wb.w;
  __syncthreads();
  float acc[8][8] = {}; // [token][code]
  for (int it = 0; it < 16; ++it) {
    int cur = it & 1;
    if (it < 15) {
      int kc = (it + 1) * 16;
      xa = *(const float4*)(xrow + kc);
      xb = *(const float4*)(xrow + kc + 4);
      wa = *(const float4*)(erow + kc);
      wb = *(const float4*)(erow + kc + 4);
    }
    float (*xsb)[128] = xs[cur];
    float (*esb)[128] = es[cur];
#pragma unroll
    for (int kk = 0; kk < 16; ++kk) {
      float4 xv0 = *(const float4*)&xsb[kk][ty * 4];
      float4 xv1 = *(const float4*)&xsb[kk][64 + ty * 4];
      float4 wv0 = *(const float4*)&esb[kk][tx * 4];
      float4 wv1 = *(const float4*)&esb[kk][64 + tx * 4];
      float xr[8] = {xv0.x, xv0.y, xv0.z, xv0.w, xv1.x, xv1.y, xv1.z, xv1.w};
      float wr[8] = {wv0.x, wv0.y, wv0.z, wv0.w, wv1.x, wv1.y, wv1.z, wv1.w};
#pragma unroll
      for (int i = 0; i < 8; ++i)
#pragma unroll
        for (int j = 0; j < 8; ++j)
          acc[i][j] = fmaf(xr[i], wr[j], acc[i][j]);
    }
    if (it < 15) {
      int nb = cur ^ 1;
      xs[nb][lh * 8 + 0][lr] = xa.x; xs[nb][lh * 8 + 1][lr] = xa.y;
      xs[nb][lh * 8 + 2][lr] = xa.z; xs[nb][lh * 8 + 3][lr] = xa.w;
      xs[nb][lh * 8 + 4][lr] = xb.x; xs[nb][lh * 8 + 5][lr] = xb.y;
      xs[nb][lh * 8 + 6][lr] = xb.z; xs[nb][lh * 8 + 7][lr] = xb.w;
      es[nb][lh * 8 + 0][lr] = wa.x; es[nb][lh * 8 + 1][lr] = wa.y;
      es[nb][lh * 8 + 2][lr] = wa.z; es[nb][lh * 8 + 3][lr] = wa.w;
      es[nb][lh * 8 + 4][lr] = wb.x; es[nb][lh * 8 + 5][lr] = wb.y;
      es[nb][lh * 8 + 6][lr] = wb.z; es[nb][lh * 8 + 7][lr] = wb.w;
      __syncthreads();
    }
  }
#pragma unroll
  for (int i = 0; i < 8; ++i) {
    int tok = (i >> 2) * 64 + ty * 4 + (i & 3);
    float* ob = sim + (size_t)(b0 + tok) * NE + j0;
    float4 lo = make_float4(acc[i][0], acc[i][1], acc[i][2], acc[i][3]);
    float4 hi = make_float4(acc[i][4], acc[i][5], acc[i][6], acc[i][7]);
    *(float4*)(ob + tx * 4) = lo;
    *(float4*)(ob + 64 + tx * 4) = hi;
  }
}

// ---------------- K8: diversity loss rows ----------------
__global__ __launch_bounds__(256) void k_div(const float* __restrict__ sim, const int* __restrict__ idxs,
                                             const int* __restrict__ label, double* __restrict__ div_sum) {
  __shared__ int lab[NE];
  int tid = threadIdx.x;
  lab[tid] = label[tid];
  lab[256 + tid] = label[256 + tid];
  __syncthreads();
  int wv = tid >> 6, ln = tid & 63;
  int b = blockIdx.x * 4 + wv;
  int ind0 = idxs[b]; // expert 0
  int clu = lab[ind0];
  const float* sr = sim + (size_t)b * NE;
  double vals[8];
  double mx = -1e300;
  int ys = 1024;
#pragma unroll
  for (int c = 0; c < 8; ++c) {
    int j = ln + 64 * c;
    double vv = (double)sr[j];
    if (j == ind0) vv -= 1e12;
    vals[c] = vv;
    mx = fmax(mx, vv);
    if (lab[j] == clu && j != ind0 && j < ys) ys = j;
  }
  for (int o = 32; o > 0; o >>= 1) {
    mx = fmax(mx, __shfl_xor(mx, o, 64));
    ys = min(ys, __shfl_xor(ys, o, 64));
  }
  int y = (ys >= 1024) ? 0 : ys;
  double se = 0.0, vy = 0.0;
#pragma unroll
  for (int c = 0; c < 8; ++c) {
    int j = ln + 64 * c;
    se += exp(vals[c] - mx);
    if (j == y) vy = vals[c];
  }
  for (int o = 32; o > 0; o >>= 1) {
    se += __shfl_xor(se, o, 64);
    vy += __shfl_xor(vy, o, 64);
  }
  if (ln == 0) {
    double lse = mx + log(se);
    atomicAdd(div_sum, lse - vy);
  }
}

// ---------------- K9: loss assembly ----------------
__global__ void k_loss(const double* __restrict__ sums, float* __restrict__ out) {
  double mse = sums[0] / 2097152.0;
  double dv = sums[1] / 8192.0;
  double loss = (mse + 0.25 * mse) + dv;
  out[0] = (float)loss;
}

extern "C" void kernel_launch(void* const* d_in, const int* in_sizes, int n_in,
                              void* d_out, int out_size, void* d_ws, size_t ws_size,
                              hipStream_t stream) {
  (void)in_sizes; (void)n_in; (void)out_size;
  const float* x = (const float*)d_in[0];
  const int* label = (const int*)d_in[1];
  const float* gate = (const float*)d_in[3];
  const float* emb = (const float*)d_in[4];
  float* out = (float*)d_out;
  float* out0 = out;
  float* outLoss = out + (size_t)NTOK * EDIM;
  float* outIdx = out + (size_t)NTOK * EDIM + 1;

  char* w = (char*)d_ws;
  size_t off = 0;
  auto alloc = [&](size_t bytes) -> void* {
    void* p = w + off;
    off += (bytes + 15) & ~(size_t)15;
    return p;
  };
  float* bigF = (float*)alloc((size_t)NEXPALL * NE * NTOK * 4); // d (f32) -> B (u32); later sim (f32)
  unsigned* bigU = (unsigned*)bigF;
  float* sim = (float*)bigF;
  unsigned* colminA = (unsigned*)alloc((size_t)NEXPALL * NTOK * 4);
  double* cml = (double*)alloc((size_t)NEXPALL * NTOK * 8);
  double* v = (double*)alloc((size_t)NEXPALL * NTOK * 8); // v0 (k_prep/k_build), then loop v
  double* r0 = (double*)alloc((size_t)NEXPALL * NE * 8);
  double* racc = (double*)alloc((size_t)NEXPALL * NE * 8);
  double* uprev = (double*)alloc((size_t)NEXPALL * NE * 8);
  float* sxF = (float*)alloc((size_t)NTOK * 4);
  float* swF = (float*)alloc((size_t)NEXPALL * NE * 4);
  unsigned* dmaxA = (unsigned*)alloc(NEXPALL * 4);
  unsigned* dminA = (unsigned*)alloc(NEXPALL * 4);
  int* conv_iter = (int*)alloc(NEXPALL * 4);
  int* idxs = (int*)alloc((size_t)NEXPALL * NTOK * 4);
  float* xq = (float*)alloc((size_t)NTOK * EDIM * 4);
  double* sums = (double*)alloc(2 * 8);
  if (off > ws_size) return; // insufficient workspace

  k_init<<<352, 256, 0, stream>>>(colminA, r0, uprev, dmaxA, dminA, conv_iter, sums);
  k_npsq<<<NTOK / 16, 256, 0, stream>>>(x, sxF, NTOK);
  k_npsq<<<(NEXPALL * NE) / 16, 256, 0, stream>>>(emb, swF, NEXPALL * NE);
  k_gemm_d<<<dim3(64, 4, NEXPALL), 256, 0, stream>>>(x, emb, sxF, swF, bigF, colminA, dmaxA, dminA);
  k_prep<<<dim3(32, NEXPALL), 256, 0, stream>>>(colminA, dmaxA, dminA, cml, v);
  k_build<<<dim3(4, NE, NEXPALL), 256, 0, stream>>>(bigF, dmaxA, dminA, cml, v, r0);
  // iterations 1..99 produce r_99 in racc (frozen experts keep their converged r);
  // final argmax uses u_100 = 1/(512 r_99). All cross-block communication crosses a
  // dispatch boundary (racc: rowsum_t -> colsum_{t+1}; v: colsum_t -> rowsum_t).
  for (int t = 1; t <= NITER - 1; ++t) {
    const double* rsrc = (t == 1) ? r0 : racc;
    k_colsum<<<dim3(64, NEXPALL), 256, 0, stream>>>(bigU, rsrc, v, uprev, conv_iter, t);
    k_rowsum<<<dim3(64, NEXPALL), 256, 0, stream>>>(bigU, v, racc, conv_iter, t);
  }
  k_final<<<dim3(64, NEXPALL), 256, 0, stream>>>(bigU, racc, idxs);
  k_mix<<<NTOK / 8, 256, 0, stream>>>(x, gate, emb, idxs, xq, out0, outIdx, sums);
  k_simgemm<<<dim3(64, 4), 256, 0, stream>>>(xq, emb, sim);
  k_div<<<NTOK / 4, 256, 0, stream>>>(sim, idxs, label, sums + 1);
  k_loss<<<1, 1, 0, stream>>>(sums, outLoss);
}

// Round 10
// 1226.833 us; speedup vs baseline: 2.0900x; 2.0900x over previous
//
#include <hip/hip_runtime.h>
#include <cstdint>
#include <cstddef>

#define NTOK 8192
#define NE 512
#define EDIM 256
#define NEXPALL 11
#define NITER 100

static __device__ __forceinline__ double wredsum(double x) {
  for (int o = 32; o > 0; o >>= 1) x += __shfl_down(x, o, 64);
  return x;
}

static constexpr double S32 = 2.3283064365386963e-10; // 2^-32
static constexpr double Q32 = 4294967296.0;           // 2^32

// ---------------- init ----------------
__global__ void k_init(unsigned* colmin, double* r0, double* uprev,
                       unsigned* dmaxA, unsigned* dminA, int* conv_iter, double* sums) {
  int i = blockIdx.x * 256 + threadIdx.x;
  if (i < NEXPALL * NTOK) colmin[i] = 0x7F800000u; // +inf f32
  if (i < NEXPALL * NE) { r0[i] = 0.0; uprev[i] = 0.0; }
  if (i < NEXPALL) { dmaxA[i] = 0u; dminA[i] = 0x7F800000u; conv_iter[i] = 1 << 30; }
  if (i < 2) sums[i] = 0.0;
}

// ---------------- numpy-pairwise sum of squares (f32, bit-exact tree) ----------------
__global__ __launch_bounds__(256) void k_npsq(const float* __restrict__ p, float* __restrict__ o, int rows) {
  int r = blockIdx.x * 16 + (threadIdx.x >> 4);
  int l = threadIdx.x & 15;
  if (r >= rows) return;
  const float* a = p + (size_t)r * EDIM;
  int leaf = l >> 3;
  int j = l & 7;
  const float* base = a + leaf * 128 + j;
  float acc = __fmul_rn(base[0], base[0]);
#pragma unroll
  for (int i = 8; i < 128; i += 8) {
    float v = base[i];
    acc = __fadd_rn(acc, __fmul_rn(v, v));
  }
  acc = __fadd_rn(acc, __shfl_xor(acc, 1, 64));
  acc = __fadd_rn(acc, __shfl_xor(acc, 2, 64));
  acc = __fadd_rn(acc, __shfl_xor(acc, 4, 64));
  float other = __shfl_xor(acc, 8, 64);
  float tot = (leaf == 0) ? __fadd_rn(acc, other) : __fadd_rn(other, acc);
  if (l == 0) o[r] = tot;
}

// ---------------- K1: f32 GEMM, 128x128 block tile, 8x8 register tile ----------------
// (256,2) is the measured-good config (VGPR 116, no spill). (256,4) spilled (r4);
// double-buffered LDS also spilled (r9: VGPR 128 + 4.7 GB scratch writes). This
// single-buffer 2-barrier form at 319 us / VALUBusy 76% is the verified optimum.
__global__ __launch_bounds__(256, 2) void k_gemm_d(const float* __restrict__ x, const float* __restrict__ emb,
                                                   const float* __restrict__ sx, const float* __restrict__ sw,
                                                   float* __restrict__ bigF,
                                                   unsigned* __restrict__ colminA,
                                                   unsigned* __restrict__ dmaxA,
                                                   unsigned* __restrict__ dminA) {
  int bx = blockIdx.x, by = blockIdx.y, e = blockIdx.z;
  int tid = threadIdx.x;
  int tx = tid & 15, ty = tid >> 4;
  int b0 = bx * 128, k0 = by * 128;

  __shared__ float xs[16][128]; // [k][token]
  __shared__ float es[16][128]; // [k][code]
  __shared__ float sxs[128];
  __shared__ float sws[128];
  __shared__ unsigned colm[128];
  __shared__ float wrx[4], wrn[4];

  if (tid < 128) { sxs[tid] = sx[b0 + tid]; colm[tid] = 0x7F800000u; }
  else { sws[tid - 128] = sw[e * NE + k0 + tid - 128]; }

  int lr = tid & 127;  // token / code row for staging
  int lh = tid >> 7;   // k sub-offset 0 or 8
  const float* xrow = x + (size_t)(b0 + lr) * EDIM + lh * 8;
  const float* wrow = emb + ((size_t)e * NE + k0 + lr) * EDIM + lh * 8;

  float4 xa = *(const float4*)(xrow + 0);
  float4 xb = *(const float4*)(xrow + 4);
  float4 wa = *(const float4*)(wrow + 0);
  float4 wb = *(const float4*)(wrow + 4);

  float acc[8][8] = {};

  for (int kc = 0; kc < EDIM; kc += 16) {
    __syncthreads();
    xs[lh * 8 + 0][lr] = xa.x; xs[lh * 8 + 1][lr] = xa.y;
    xs[lh * 8 + 2][lr] = xa.z; xs[lh * 8 + 3][lr] = xa.w;
    xs[lh * 8 + 4][lr] = xb.x; xs[lh * 8 + 5][lr] = xb.y;
    xs[lh * 8 + 6][lr] = xb.z; xs[lh * 8 + 7][lr] = xb.w;
    es[lh * 8 + 0][lr] = wa.x; es[lh * 8 + 1][lr] = wa.y;
    es[lh * 8 + 2][lr] = wa.z; es[lh * 8 + 3][lr] = wa.w;
    es[lh * 8 + 4][lr] = wb.x; es[lh * 8 + 5][lr] = wb.y;
    es[lh * 8 + 6][lr] = wb.z; es[lh * 8 + 7][lr] = wb.w;
    __syncthreads();
    if (kc + 16 < EDIM) { // prefetch next k-tile; hides under compute
      xa = *(const float4*)(xrow + kc + 16);
      xb = *(const float4*)(xrow + kc + 20);
      wa = *(const float4*)(wrow + kc + 16);
      wb = *(const float4*)(wrow + kc + 20);
    }
#pragma unroll
    for (int kk = 0; kk < 16; ++kk) {
      float4 xv0 = *(const float4*)&xs[kk][tx * 4];
      float4 xv1 = *(const float4*)&xs[kk][64 + tx * 4];
      float4 wv0 = *(const float4*)&es[kk][ty * 4];
      float4 wv1 = *(const float4*)&es[kk][64 + ty * 4];
      float xr[8] = {xv0.x, xv0.y, xv0.z, xv0.w, xv1.x, xv1.y, xv1.z, xv1.w};
      float wr[8] = {wv0.x, wv0.y, wv0.z, wv0.w, wv1.x, wv1.y, wv1.z, wv1.w};
#pragma unroll
      for (int i = 0; i < 8; ++i)
#pragma unroll
        for (int j = 0; j < 8; ++j)
          acc[i][j] = fmaf(xr[i], wr[j], acc[i][j]);
    }
  }

  // epilogue: d = sx + sw - 2*acc (in place), stats, transposed store
  float dmx = -3.0e38f, dmn = 3.0e38f;
#pragma unroll
  for (int i = 0; i < 8; ++i) {
    int tokL = (i >> 2) * 64 + tx * 4 + (i & 3);
    float sxv = sxs[tokL];
    float cmin = 3.0e38f;
#pragma unroll
    for (int j = 0; j < 8; ++j) {
      int codeL = (j >> 2) * 64 + ty * 4 + (j & 3);
      float m2 = __fmul_rn(2.0f, acc[i][j]);
      float dv = __fsub_rn(__fadd_rn(sxv, sws[codeL]), m2);
      acc[i][j] = dv;
      dmx = fmaxf(dmx, dv); dmn = fminf(dmn, dv);
      cmin = fminf(cmin, dv);
    }
    atomicMin(&colm[tokL], __float_as_uint(cmin)); // d > 0 -> uint order == float order
  }
  for (int o = 32; o > 0; o >>= 1) {
    dmx = fmaxf(dmx, __shfl_down(dmx, o, 64));
    dmn = fminf(dmn, __shfl_down(dmn, o, 64));
  }
  int wvi = tid >> 6, ln = tid & 63;
  if (ln == 0) { wrx[wvi] = dmx; wrn[wvi] = dmn; }
  __syncthreads();
  if (tid == 0) {
    float m1 = fmaxf(fmaxf(wrx[0], wrx[1]), fmaxf(wrx[2], wrx[3]));
    float m2 = fminf(fminf(wrn[0], wrn[1]), fminf(wrn[2], wrn[3]));
    atomicMax(dmaxA + e, __float_as_uint(m1));
    atomicMin(dminA + e, __float_as_uint(m2));
  }
  if (tid < 128) atomicMin(colminA + (size_t)e * NTOK + b0 + tid, colm[tid]);
#pragma unroll
  for (int j2 = 0; j2 < 2; ++j2)
#pragma unroll
    for (int cc = 0; cc < 4; ++cc) {
      int code = j2 * 64 + ty * 4 + cc;
      int cj = j2 * 4 + cc;
      float* ob = bigF + ((size_t)e * NE + k0 + code) * NTOK + b0;
      float4 lo = make_float4(acc[0][cj], acc[1][cj], acc[2][cj], acc[3][cj]);
      float4 hi = make_float4(acc[4][cj], acc[5][cj], acc[6][cj], acc[7][cj]);
      *(float4*)(ob + tx * 4) = lo;
      *(float4*)(ob + 64 + tx * 4) = hi;
    }
}

// ---------------- K2: per-token colmax logit + v0 ----------------
__global__ __launch_bounds__(256) void k_prep(const unsigned* __restrict__ colminA,
                                              const unsigned* __restrict__ dmaxA,
                                              const unsigned* __restrict__ dminA,
                                              double* __restrict__ cml, double* __restrict__ v) {
  int e = blockIdx.y;
  int b = blockIdx.x * 256 + threadIdx.x;
  float mx = __uint_as_float(dmaxA[e]);
  float mn = __uint_as_float(dminA[e]);
  float mid = __fmul_rn(__fadd_rn(mx, mn), 0.5f);
  float amp = __fadd_rn(__fsub_rn(mx, mid), 1e-5f);
  float cminf = __uint_as_float(colminA[(size_t)e * NTOK + b]);
  float dn = __fdiv_rn(__fsub_rn(cminf, mid), amp);
  double l = (-(double)dn) / 0.01;
  cml[(size_t)e * NTOK + b] = l;
  v[(size_t)e * NTOK + b] = exp(l);
}

// ---------------- K3: build B (u32 fixed point of 1-B, in place) + r0 ----------------
__global__ __launch_bounds__(256) void k_build(float* __restrict__ bigF,
                                               const unsigned* __restrict__ dmaxA,
                                               const unsigned* __restrict__ dminA,
                                               const double* __restrict__ cml, const double* __restrict__ v0,
                                               double* __restrict__ r0) {
  int bx = blockIdx.x, k = blockIdx.y, e = blockIdx.z;
  int tid = threadIdx.x;
  float mx = __uint_as_float(dmaxA[e]);
  float mn = __uint_as_float(dminA[e]);
  float mid = __fmul_rn(__fadd_rn(mx, mn), 0.5f);
  float amp = __fadd_rn(__fsub_rn(mx, mid), 1e-5f);
  size_t rb = ((size_t)e * NE + k) * NTOK;
  int cb = bx * 2048 + tid * 8;
  float4 fa = *(const float4*)(bigF + rb + cb);
  float4 fb = *(const float4*)(bigF + rb + cb + 4);
  float din[8] = {fa.x, fa.y, fa.z, fa.w, fb.x, fb.y, fb.z, fb.w};
  unsigned qo[8];
  double racc = 0.0;
#pragma unroll
  for (int j = 0; j < 8; ++j) {
    int b = cb + j;
    float dn = __fdiv_rn(__fsub_rn(din[j], mid), amp);
    double l = (-(double)dn) / 0.01;
    double t = l - cml[(size_t)e * NTOK + b]; // <= 0, == 0 at per-token max logit
    double Bv = exp(t);
    double qd = (1.0 - Bv) * Q32;
    qd = fmin(fmax(qd, 0.0), 4294967295.0);
    unsigned q = (unsigned)llrint(qd);
    qo[j] = q;
    double Bq = fma(-(double)q, S32, 1.0);
    racc = fma(Bq, v0[(size_t)e * NTOK + b], racc);
  }
  uint4 oa = make_uint4(qo[0], qo[1], qo[2], qo[3]);
  uint4 ob2 = make_uint4(qo[4], qo[5], qo[6], qo[7]);
  *(uint4*)((unsigned*)bigF + rb + cb) = oa;
  *(uint4*)((unsigned*)bigF + rb + cb + 4) = ob2;
  racc = wredsum(racc);
  __shared__ double pr[4];
  int wv = tid >> 6, ln = tid & 63;
  if (ln == 0) pr[wv] = racc;
  __syncthreads();
  if (tid == 0) atomicAdd(&r0[e * NE + k], (pr[0] + pr[1]) + (pr[2] + pr[3]));
}

// ---------------- K4a: col sums -> v (one dispatch; u recomputed per block) ----------
// grid (64, 11): block = 128-column stripe. Reads r_{t-1} from racc (r0 at t=1) —
// written by the PREVIOUS dispatch (k_rowsum / k_build) -> cross-dispatch visibility
// only; no same-dispatch cross-block reads anywhere. sub==0 block also runs the
// convergence check (u_t vs u_{t-1}).
__global__ __launch_bounds__(256) void k_colsum(const unsigned* __restrict__ bigU,
                                                const double* __restrict__ rsrc,
                                                double* __restrict__ vout,
                                                double* __restrict__ uprev,
                                                int* __restrict__ conv_iter, int t) {
  int e = blockIdx.y, sub = blockIdx.x, tid = threadIdx.x;
  if (t > ((volatile int*)conv_iter)[e]) return;
  __shared__ double us[NE];
  __shared__ double part[256];
  __shared__ int okf;
  if (tid == 0) okf = 1;
  int k2 = tid * 2;
  double u0 = 1.0 / (512.0 * rsrc[e * NE + k2]);
  double u1 = 1.0 / (512.0 * rsrc[e * NE + k2 + 1]);
  us[k2] = u0; us[k2 + 1] = u1;
  __syncthreads();
  if (sub == 0) {
    double p0 = uprev[e * NE + k2], p1 = uprev[e * NE + k2 + 1];
    bool ok = (fabs(u0 - p0) <= 1e-13 * fabs(u0)) && (fabs(u1 - p1) <= 1e-13 * fabs(u1));
    if (!ok) okf = 0;
    uprev[e * NE + k2] = u0; uprev[e * NE + k2 + 1] = u1;
  }
  __syncthreads();
  if (sub == 0 && tid == 0 && okf) atomicMin(conv_iter + e, t);

  // column sums: 2 threads per column (k-halves)
  int lcol = tid & 127, half = tid >> 7;
  int col = sub * 128 + lcol;
  const unsigned* cp = bigU + (size_t)e * NE * NTOK + col;
  int kh = half * 256;
  double c0 = 0, c1 = 0, c2 = 0, c3 = 0;
#pragma unroll 4
  for (int k = kh; k < kh + 256; k += 4) {
    unsigned q0 = cp[(size_t)(k + 0) * NTOK];
    unsigned q1 = cp[(size_t)(k + 1) * NTOK];
    unsigned q2 = cp[(size_t)(k + 2) * NTOK];
    unsigned q3 = cp[(size_t)(k + 3) * NTOK];
    c0 = fma(us[k + 0], fma(-(double)q0, S32, 1.0), c0);
    c1 = fma(us[k + 1], fma(-(double)q1, S32, 1.0), c1);
    c2 = fma(us[k + 2], fma(-(double)q2, S32, 1.0), c2);
    c3 = fma(us[k + 3], fma(-(double)q3, S32, 1.0), c3);
  }
  part[tid] = (c0 + c1) + (c2 + c3);
  __syncthreads();
  if (tid < 128)
    vout[(size_t)e * NTOK + sub * 128 + tid] = 1.0 / (8192.0 * (part[tid] + part[tid + 128]));
}

// ---------------- K4b: row sums -> racc (plain stores; block owns its k's) ----------
// grid (64, 11): block = 8 contiguous k-rows. No atomics, no zeroing, no parity.
__global__ __launch_bounds__(256) void k_rowsum(const unsigned* __restrict__ bigU,
                                                const double* __restrict__ v,
                                                double* __restrict__ racc,
                                                const int* __restrict__ conv_iter, int t) {
  int e = blockIdx.y, sub = blockIdx.x, tid = threadIdx.x;
  if (t > ((volatile int*)conv_iter)[e]) return;
  size_t ebase = (size_t)e * NE * NTOK;
  const double* vb = v + (size_t)e * NTOK;
  double p[8] = {0, 0, 0, 0, 0, 0, 0, 0};
  for (int i = 0; i < 8; ++i) {
    int c = i * 1024 + tid * 4;
    double2 va = *(const double2*)(vb + c);
    double2 vc = *(const double2*)(vb + c + 2);
#pragma unroll
    for (int kk = 0; kk < 8; ++kk) {
      const unsigned* rp = bigU + ebase + (size_t)(sub * 8 + kk) * NTOK + c;
      uint4 q = *(const uint4*)rp;
      p[kk] = fma(va.x, fma(-(double)q.x, S32, 1.0), p[kk]);
      p[kk] = fma(va.y, fma(-(double)q.y, S32, 1.0), p[kk]);
      p[kk] = fma(vc.x, fma(-(double)q.z, S32, 1.0), p[kk]);
      p[kk] = fma(vc.y, fma(-(double)q.w, S32, 1.0), p[kk]);
    }
  }
  __shared__ double pr[8][4];
  int wv = tid >> 6, ln = tid & 63;
#pragma unroll
  for (int kk = 0; kk < 8; ++kk) {
    double s = wredsum(p[kk]);
    if (ln == 0) pr[kk][wv] = s;
  }
  __syncthreads();
  if (tid < 8)
    racc[e * NE + sub * 8 + tid] = (pr[tid][0] + pr[tid][1]) + (pr[tid][2] + pr[tid][3]);
}

// ---------------- K5: final argmax per token (u from racc; v cancels) ----------------
__global__ __launch_bounds__(256) void k_final(const unsigned* __restrict__ bigU,
                                               const double* __restrict__ racc,
                                               int* __restrict__ idxs) {
  int e = blockIdx.y, sub = blockIdx.x, tid = threadIdx.x;
  __shared__ double us[NE];
  __shared__ double bv[256];
  __shared__ int bix[256];
  int k2 = tid * 2;
  us[k2] = 1.0 / (512.0 * racc[e * NE + k2]);
  us[k2 + 1] = 1.0 / (512.0 * racc[e * NE + k2 + 1]);
  __syncthreads();
  int lcol = tid & 127, half = tid >> 7;
  int col = sub * 128 + lcol;
  const unsigned* cp = bigU + (size_t)e * NE * NTOK + col;
  double best = -1.0;
  int bi = 0;
  int kh = half * 256;
#pragma unroll 4
  for (int k = kh; k < kh + 256; ++k) {
    double s = us[k] * fma(-(double)cp[(size_t)k * NTOK], S32, 1.0);
    if (s > best) { best = s; bi = k; }
  }
  bv[tid] = best; bix[tid] = bi;
  __syncthreads();
  if (tid < 128) {
    // half-0 ks are all smaller; strict > keeps first-max semantics
    int r = (bv[tid + 128] > bv[tid]) ? bix[tid + 128] : bix[tid];
    idxs[(size_t)e * NTOK + col] = r;
  }
}

// ---------------- K6: mixture, out0, mse partial, index output ----------------
__global__ __launch_bounds__(256) void k_mix(const float* __restrict__ x, const float* __restrict__ gate,
                                             const float* __restrict__ emb, const int* __restrict__ idxs,
                                             float* __restrict__ xq, float* __restrict__ out0,
                                             float* __restrict__ outIdx, double* __restrict__ mse_sum) {
  int tid = threadIdx.x;
  int sub = tid >> 5, lane = tid & 31;
  int tok = blockIdx.x * 8 + sub;
  float acc[8] = {0, 0, 0, 0, 0, 0, 0, 0};
#pragma unroll
  for (int ee = 0; ee < 10; ++ee) {
    int id = idxs[(size_t)ee * NTOK + tok];
    float g = gate[tok * 10 + ee];
    const float* er = emb + ((size_t)ee * NE + id) * EDIM + lane;
#pragma unroll
    for (int dd = 0; dd < 8; ++dd) acc[dd] = fmaf(g, er[32 * dd], acc[dd]);
  }
  int id10 = idxs[(size_t)10 * NTOK + tok];
  const float* es = emb + ((size_t)10 * NE + id10) * EDIM + lane;
  double ms = 0.0;
#pragma unroll
  for (int dd = 0; dd < 8; ++dd) {
    int d = lane + 32 * dd;
    float q = 0.95f * acc[dd] + 0.05f * es[32 * dd];
    float xv = x[(size_t)tok * EDIM + d];
    float df = q - xv;
    out0[(size_t)tok * EDIM + d] = xv + df;
    xq[(size_t)tok * EDIM + d] = q;
    ms += (double)df * (double)df;
  }
  ms = wredsum(ms);
  __shared__ double pr[4];
  int wv = tid >> 6, ln = tid & 63;
  if (ln == 0) pr[wv] = ms;
  __syncthreads();
  if (tid == 0) atomicAdd(mse_sum, (pr[0] + pr[1]) + (pr[2] + pr[3]));
  if (lane == 0) {
    const float* gr = gate + tok * 10;
    float bg = gr[0];
    int be = 0;
#pragma unroll
    for (int ee = 1; ee < 10; ++ee) { float g = gr[ee]; if (g > bg) { bg = g; be = ee; } }
    outIdx[tok] = (float)idxs[(size_t)be * NTOK + tok];
  }
}

// ---------------- K7: sim = x_q @ emb0^T, same 128x128 / 8x8 structure ----------------
__global__ __launch_bounds__(256, 2) void k_simgemm(const float* __restrict__ xq, const float* __restrict__ emb,
                                                    float* __restrict__ sim) {
  int bx = blockIdx.x, by = blockIdx.y, tid = threadIdx.x;
  int tx = tid & 15, ty = tid >> 4;
  int b0 = bx * 128, j0 = by * 128;
  __shared__ float xs[16][128]; // [k][token]
  __shared__ float es[16][128]; // [k][code]
  int lr = tid & 127;
  int lh = tid >> 7;
  const float* xrow = xq + (size_t)(b0 + lr) * EDIM + lh * 8;
  const float* erow = emb + (size_t)(j0 + lr) * EDIM + lh * 8; // expert 0
  float4 xa = *(const float4*)(xrow + 0);
  float4 xb = *(const float4*)(xrow + 4);
  float4 wa = *(const float4*)(erow + 0);
  float4 wb = *(const float4*)(erow + 4);
  float acc[8][8] = {}; // [token][code]
  for (int kc = 0; kc < EDIM; kc += 16) {
    __syncthreads();
    xs[lh * 8 + 0][lr] = xa.x; xs[lh * 8 + 1][lr] = xa.y;
    xs[lh * 8 + 2][lr] = xa.z; xs[lh * 8 + 3][lr] = xa.w;
    xs[lh * 8 + 4][lr] = xb.x; xs[lh * 8 + 5][lr] = xb.y;
    xs[lh * 8 + 6][lr] = xb.z; xs[lh * 8 + 7][lr] = xb.w;
    es[lh * 8 + 0][lr] = wa.x; es[lh * 8 + 1][lr] = wa.y;
    es[lh * 8 + 2][lr] = wa.z; es[lh * 8 + 3][lr] = wa.w;
    es[lh * 8 + 4][lr] = wb.x; es[lh * 8 + 5][lr] = wb.y;
    es[lh * 8 + 6][lr] = wb.z; es[lh * 8 + 7][lr] = wb.w;
    __syncthreads();
    if (kc + 16 < EDIM) {
      xa = *(const float4*)(xrow + kc + 16);
      xb = *(const float4*)(xrow + kc + 20);
      wa = *(const float4*)(erow + kc + 16);
      wb = *(const float4*)(erow + kc + 20);
    }
#pragma unroll
    for (int kk = 0; kk < 16; ++kk) {
      float4 xv0 = *(const float4*)&xs[kk][ty * 4];
      float4 xv1 = *(const float4*)&xs[kk][64 + ty * 4];
      float4 wv0 = *(const float4*)&es[kk][tx * 4];
      float4 wv1 = *(const float4*)&es[kk][64 + tx * 4];
      float xr[8] = {xv0.x, xv0.y, xv0.z, xv0.w, xv1.x, xv1.y, xv1.z, xv1.w};
      float wr[8] = {wv0.x, wv0.y, wv0.z, wv0.w, wv1.x, wv1.y, wv1.z, wv1.w};
#pragma unroll
      for (int i = 0; i < 8; ++i)
#pragma unroll
        for (int j = 0; j < 8; ++j)
          acc[i][j] = fmaf(xr[i], wr[j], acc[i][j]);
    }
  }
#pragma unroll
  for (int i = 0; i < 8; ++i) {
    int tok = (i >> 2) * 64 + ty * 4 + (i & 3);
    float* ob = sim + (size_t)(b0 + tok) * NE + j0;
    float4 lo = make_float4(acc[i][0], acc[i][1], acc[i][2], acc[i][3]);
    float4 hi = make_float4(acc[i][4], acc[i][5], acc[i][6], acc[i][7]);
    *(float4*)(ob + tx * 4) = lo;
    *(float4*)(ob + 64 + tx * 4) = hi;
  }
}

// ---------------- K8: diversity loss rows ----------------
__global__ __launch_bounds__(256) void k_div(const float* __restrict__ sim, const int* __restrict__ idxs,
                                             const int* __restrict__ label, double* __restrict__ div_sum) {
  __shared__ int lab[NE];
  int tid = threadIdx.x;
  lab[tid] = label[tid];
  lab[256 + tid] = label[256 + tid];
  __syncthreads();
  int wv = tid >> 6, ln = tid & 63;
  int b = blockIdx.x * 4 + wv;
  int ind0 = idxs[b]; // expert 0
  int clu = lab[ind0];
  const float* sr = sim + (size_t)b * NE;
  double vals[8];
  double mx = -1e300;
  int ys = 1024;
#pragma unroll
  for (int c = 0; c < 8; ++c) {
    int j = ln + 64 * c;
    double vv = (double)sr[j];
    if (j == ind0) vv -= 1e12;
    vals[c] = vv;
    mx = fmax(mx, vv);
    if (lab[j] == clu && j != ind0 && j < ys) ys = j;
  }
  for (int o = 32; o > 0; o >>= 1) {
    mx = fmax(mx, __shfl_xor(mx, o, 64));
    ys = min(ys, __shfl_xor(ys, o, 64));
  }
  int y = (ys >= 1024) ? 0 : ys;
  double se = 0.0, vy = 0.0;
#pragma unroll
  for (int c = 0; c < 8; ++c) {
    int j = ln + 64 * c;
    se += exp(vals[c] - mx);
    if (j == y) vy = vals[c];
  }
  for (int o = 32; o > 0; o >>= 1) {
    se += __shfl_xor(se, o, 64);
    vy += __shfl_xor(vy, o, 64);
  }
  if (ln == 0) {
    double lse = mx + log(se);
    atomicAdd(div_sum, lse - vy);
  }
}

// ---------------- K9: loss assembly ----------------
__global__ void k_loss(const double* __restrict__ sums, float* __restrict__ out) {
  double mse = sums[0] / 2097152.0;
  double dv = sums[1] / 8192.0;
  double loss = (mse + 0.25 * mse) + dv;
  out[0] = (float)loss;
}

extern "C" void kernel_launch(void* const* d_in, const int* in_sizes, int n_in,
                              void* d_out, int out_size, void* d_ws, size_t ws_size,
                              hipStream_t stream) {
  (void)in_sizes; (void)n_in; (void)out_size;
  const float* x = (const float*)d_in[0];
  const int* label = (const int*)d_in[1];
  const float* gate = (const float*)d_in[3];
  const float* emb = (const float*)d_in[4];
  float* out = (float*)d_out;
  float* out0 = out;
  float* outLoss = out + (size_t)NTOK * EDIM;
  float* outIdx = out + (size_t)NTOK * EDIM + 1;

  char* w = (char*)d_ws;
  size_t off = 0;
  auto alloc = [&](size_t bytes) -> void* {
    void* p = w + off;
    off += (bytes + 15) & ~(size_t)15;
    return p;
  };
  float* bigF = (float*)alloc((size_t)NEXPALL * NE * NTOK * 4); // d (f32) -> B (u32); later sim (f32)
  unsigned* bigU = (unsigned*)bigF;
  float* sim = (float*)bigF;
  unsigned* colminA = (unsigned*)alloc((size_t)NEXPALL * NTOK * 4);
  double* cml = (double*)alloc((size_t)NEXPALL * NTOK * 8);
  double* v = (double*)alloc((size_t)NEXPALL * NTOK * 8); // v0 (k_prep/k_build), then loop v
  double* r0 = (double*)alloc((size_t)NEXPALL * NE * 8);
  double* racc = (double*)alloc((size_t)NEXPALL * NE * 8);
  double* uprev = (double*)alloc((size_t)NEXPALL * NE * 8);
  float* sxF = (float*)alloc((size_t)NTOK * 4);
  float* swF = (float*)alloc((size_t)NEXPALL * NE * 4);
  unsigned* dmaxA = (unsigned*)alloc(NEXPALL * 4);
  unsigned* dminA = (unsigned*)alloc(NEXPALL * 4);
  int* conv_iter = (int*)alloc(NEXPALL * 4);
  int* idxs = (int*)alloc((size_t)NEXPALL * NTOK * 4);
  float* xq = (float*)alloc((size_t)NTOK * EDIM * 4);
  double* sums = (double*)alloc(2 * 8);
  if (off > ws_size) return; // insufficient workspace

  k_init<<<352, 256, 0, stream>>>(colminA, r0, uprev, dmaxA, dminA, conv_iter, sums);
  k_npsq<<<NTOK / 16, 256, 0, stream>>>(x, sxF, NTOK);
  k_npsq<<<(NEXPALL * NE) / 16, 256, 0, stream>>>(emb, swF, NEXPALL * NE);
  k_gemm_d<<<dim3(64, 4, NEXPALL), 256, 0, stream>>>(x, emb, sxF, swF, bigF, colminA, dmaxA, dminA);
  k_prep<<<dim3(32, NEXPALL), 256, 0, stream>>>(colminA, dmaxA, dminA, cml, v);
  k_build<<<dim3(4, NE, NEXPALL), 256, 0, stream>>>(bigF, dmaxA, dminA, cml, v, r0);
  // iterations 1..99 produce r_99 in racc (frozen experts keep their converged r);
  // final argmax uses u_100 = 1/(512 r_99). All cross-block communication crosses a
  // dispatch boundary (racc: rowsum_t -> colsum_{t+1}; v: colsum_t -> rowsum_t).
  for (int t = 1; t <= NITER - 1; ++t) {
    const double* rsrc = (t == 1) ? r0 : racc;
    k_colsum<<<dim3(64, NEXPALL), 256, 0, stream>>>(bigU, rsrc, v, uprev, conv_iter, t);
    k_rowsum<<<dim3(64, NEXPALL), 256, 0, stream>>>(bigU, v, racc, conv_iter, t);
  }
  k_final<<<dim3(64, NEXPALL), 256, 0, stream>>>(bigU, racc, idxs);
  k_mix<<<NTOK / 8, 256, 0, stream>>>(x, gate, emb, idxs, xq, out0, outIdx, sums);
  k_simgemm<<<dim3(64, 4), 256, 0, stream>>>(xq, emb, sim);
  k_div<<<NTOK / 4, 256, 0, stream>>>(sim, idxs, label, sums + 1);
  k_loss<<<1, 1, 0, stream>>>(sums, outLoss);
}